// Round 1
// baseline (459.702 us; speedup 1.0000x reference)
//
#include <hip/hip_runtime.h>
#include <stdint.h>

#define GLOBAL_AS __attribute__((address_space(1)))
#define LDS_AS __attribute__((address_space(3)))

typedef int v4i  __attribute__((ext_vector_type(4)));
typedef int v16i __attribute__((ext_vector_type(16)));

static constexpr int M = 8192;
static constexpr int N = 4096;
static constexpr int K = 4096;
static constexpr float F_EPS = 1e-5f;

// ws layout: 0: wssc[3] (s_x, wscale, outscale) | 256: pmax[2048] f32 | 8448: psum[1024] f64
//            16640: xq[M*K] i8 | +32MiB: wq[N*K] i8

// ---------------- fused reductions ----------------
__global__ void reduce_kernel(const float4* __restrict__ x, const float4* __restrict__ w,
                              float* __restrict__ pmax, double* __restrict__ psum) {
    const int b = blockIdx.x;
    const int t = threadIdx.x;
    if (b < 2048) {
        float m = 0.f;
        const int n4 = M * K / 4;           // 8M float4
        int i = b * 512 + t;
        for (; i + 256 < n4; i += 2048 * 512) {
            float4 v0 = x[i];
            float4 v1 = x[i + 256];
            m = fmaxf(m, fmaxf(fmaxf(fabsf(v0.x), fabsf(v0.y)), fmaxf(fabsf(v0.z), fabsf(v0.w))));
            m = fmaxf(m, fmaxf(fmaxf(fabsf(v1.x), fabsf(v1.y)), fmaxf(fabsf(v1.z), fabsf(v1.w))));
        }
#pragma unroll
        for (int off = 32; off > 0; off >>= 1) m = fmaxf(m, __shfl_down(m, off, 64));
        __shared__ float red[4];
        if ((t & 63) == 0) red[t >> 6] = m;
        __syncthreads();
        if (t == 0) pmax[b] = fmaxf(fmaxf(red[0], red[1]), fmaxf(red[2], red[3]));
    } else {
        double s = 0.0;
        const int n4 = N * K / 4;           // 4M float4
        int i = (b - 2048) * 512 + t;
        for (; i + 256 < n4; i += 1024 * 512) {
            float4 v0 = w[i];
            float4 v1 = w[i + 256];
            s += (double)fabsf(v0.x) + (double)fabsf(v0.y) + (double)fabsf(v0.z) + (double)fabsf(v0.w);
            s += (double)fabsf(v1.x) + (double)fabsf(v1.y) + (double)fabsf(v1.z) + (double)fabsf(v1.w);
        }
#pragma unroll
        for (int off = 32; off > 0; off >>= 1) s += __shfl_down(s, off, 64);
        __shared__ double dred[4];
        if ((t & 63) == 0) dred[t >> 6] = s;
        __syncthreads();
        if (t == 0) psum[b - 2048] = dred[0] + dred[1] + dred[2] + dred[3];
    }
}

// ---------------- finalize scalars ----------------
__global__ void finalize_kernel(float* __restrict__ wssc, const float* __restrict__ pmax,
                                const double* __restrict__ psum) {
    const int t = threadIdx.x;
    float m = 0.f;
#pragma unroll
    for (int j = 0; j < 8; ++j) m = fmaxf(m, pmax[t + j * 256]);
#pragma unroll
    for (int off = 32; off > 0; off >>= 1) m = fmaxf(m, __shfl_down(m, off, 64));
    double s = psum[t] + psum[t + 256] + psum[t + 512] + psum[t + 768];
#pragma unroll
    for (int off = 32; off > 0; off >>= 1) s += __shfl_down(s, off, 64);
    __shared__ float red[4];
    __shared__ double dred[4];
    if ((t & 63) == 0) { red[t >> 6] = m; dred[t >> 6] = s; }
    __syncthreads();
    if (t == 0) {
        float gamma = fmaxf(fmaxf(fmaxf(red[0], red[1]), fmaxf(red[2], red[3])), F_EPS);
        double sum = dred[0] + dred[1] + dred[2] + dred[3];
        float wscale = (float)fmax(sum * (1.0 / ((double)N * (double)K)), (double)F_EPS);
        wssc[0] = 128.f / gamma;
        wssc[1] = wscale;
        wssc[2] = gamma * wscale / 128.f;
    }
}

// ---------------- fused quantization ----------------
__global__ void quant_kernel(const float4* __restrict__ x, const float4* __restrict__ w,
                             int* __restrict__ xq, int* __restrict__ wq,
                             const float* __restrict__ wssc) {
    const int b = blockIdx.x;
    const int t = threadIdx.x;
    if (b < 2048) {
        const float s = wssc[0];
        const int n4 = M * K / 4;
        int i = b * 512 + t;
        for (; i + 256 < n4; i += 2048 * 512) {
            float4 v0 = x[i];
            float4 v1 = x[i + 256];
            int a0 = min(127, max(-128, (int)rintf(v0.x * s)));
            int a1 = min(127, max(-128, (int)rintf(v0.y * s)));
            int a2 = min(127, max(-128, (int)rintf(v0.z * s)));
            int a3 = min(127, max(-128, (int)rintf(v0.w * s)));
            xq[i] = (a0 & 255) | ((a1 & 255) << 8) | ((a2 & 255) << 16) | (a3 << 24);
            int b0 = min(127, max(-128, (int)rintf(v1.x * s)));
            int b1 = min(127, max(-128, (int)rintf(v1.y * s)));
            int b2 = min(127, max(-128, (int)rintf(v1.z * s)));
            int b3 = min(127, max(-128, (int)rintf(v1.w * s)));
            xq[i + 256] = (b0 & 255) | ((b1 & 255) << 8) | ((b2 & 255) << 16) | (b3 << 24);
        }
    } else {
        const float ws = wssc[1];
        const int n4 = N * K / 4;
        int i = (b - 2048) * 512 + t;
        for (; i + 256 < n4; i += 1024 * 512) {
            float4 v0 = w[i];
            float4 v1 = w[i + 256];
            int a0 = min(1, max(-1, (int)rintf(v0.x / ws)));
            int a1 = min(1, max(-1, (int)rintf(v0.y / ws)));
            int a2 = min(1, max(-1, (int)rintf(v0.z / ws)));
            int a3 = min(1, max(-1, (int)rintf(v0.w / ws)));
            wq[i] = (a0 & 255) | ((a1 & 255) << 8) | ((a2 & 255) << 16) | (a3 << 24);
            int b0 = min(1, max(-1, (int)rintf(v1.x / ws)));
            int b1 = min(1, max(-1, (int)rintf(v1.y / ws)));
            int b2 = min(1, max(-1, (int)rintf(v1.z / ws)));
            int b3 = min(1, max(-1, (int)rintf(v1.w / ws)));
            wq[i + 256] = (b0 & 255) | ((b1 & 255) << 8) | ((b2 & 255) << 16) | (b3 << 24);
        }
    }
}

// ---------------- int8 GEMM: 256x256 block, 8 waves (each 128x64), BK=64 ----------------
// 4 LDS buffers, depth-3 prefetch, counted vmcnt(12) — loads for t+1..t+3 stay in flight
// LDS chunked layout: chunk = 16 rows x 4 kblks (1KB); slot s: k=s>>4, rho=((s&15)-4k)&15
// frag read offset(row r, kblk k) = (r>>4)*1024 + k*256 + (((r&15)+4k)&15)*16 -> 0 bank conflicts
__global__ __launch_bounds__(512, 2) void gemm_kernel(
    const int8_t* __restrict__ xq, const int8_t* __restrict__ wq,
    const float* __restrict__ bias, const float* __restrict__ wssc,
    float* __restrict__ out) {

    __shared__ __align__(16) int8_t As[4][256 * 64];   // 64 KiB
    __shared__ __align__(16) int8_t Bs[4][256 * 64];   // 64 KiB

    const int t = threadIdx.x;
    const int lane = t & 63;
    const int wv = t >> 6;          // 0..7
    const int half = lane >> 5;
    const int lr = lane & 31;
    const int wm0 = (wv >> 2) * 128;   // wave m offset within block (2 waves in M)
    const int wn0 = (wv & 3) * 64;     // wave n offset within block (4 waves in N)

    // XCD-chunked swizzle: 512 blocks = 8 chunks of 64; chunk c covers an 8x8 block sub-grid.
    // grid tiles: 32 (M) x 16 (N). chunk row = xcd>>1 (0..3), chunk col = xcd&1 (0..1).
    const int bid = blockIdx.x;
    const int xcd = bid & 7;
    const int cix = bid >> 3;          // 0..63 within chunk
    const int m0 = ((xcd >> 1) * 8 + (cix >> 3)) * 256;
    const int n0 = ((xcd & 1) * 8 + (cix & 7)) * 256;

    // ---- staging source pointers: A 2 slots/thread, B 2 slots/thread (512 thr) ----
    const GLOBAL_AS int8_t* aSrc[2];
    const GLOBAL_AS int8_t* bSrc[2];
    int aLds[2], bLds[2];
#pragma unroll
    for (int j = 0; j < 2; ++j) {
        int idx = j * 512 + t;       // 0..1023
        int c = idx >> 6;            // 16 chunks of 16 rows = 256 rows
        int s = idx & 63;
        int k = s >> 4;
        int rho = ((s & 15) - 4 * k) & 15;
        int row = c * 16 + rho;
        aSrc[j] = (const GLOBAL_AS int8_t*)(xq + (size_t)(m0 + row) * K + k * 16);
        bSrc[j] = (const GLOBAL_AS int8_t*)(wq + (size_t)(n0 + row) * K + k * 16);
        aLds[j] = idx * 16;
        bLds[j] = idx * 16;
    }

    // ---- fragment LDS offsets ----
    int aOff[2][4], bOff[2][2];
#pragma unroll
    for (int ks = 0; ks < 2; ++ks) {
        int k = ks * 2 + half;
#pragma unroll
        for (int q = 0; q < 4; ++q) {
            int r = wm0 + q * 32 + lr;
            aOff[ks][q] = (r >> 4) * 1024 + k * 256 + (((r & 15) + 4 * k) & 15) * 16;
        }
#pragma unroll
        for (int q = 0; q < 2; ++q) {
            int r = wn0 + q * 32 + lr;
            bOff[ks][q] = (r >> 4) * 1024 + k * 256 + (((r & 15) + 4 * k) & 15) * 16;
        }
    }

    v16i acc[4][2];
#pragma unroll
    for (int mt = 0; mt < 4; ++mt)
#pragma unroll
        for (int nt = 0; nt < 2; ++nt)
#pragma unroll
            for (int e = 0; e < 16; ++e) acc[mt][nt][e] = 0;

    auto stage = [&](int kt, int8_t* A, int8_t* B) {
#pragma unroll
        for (int j = 0; j < 2; ++j)
            __builtin_amdgcn_global_load_lds((const GLOBAL_AS void*)(aSrc[j] + kt),
                                             (LDS_AS void*)(A + aLds[j]), 16, 0, 0);
#pragma unroll
        for (int j = 0; j < 2; ++j)
            __builtin_amdgcn_global_load_lds((const GLOBAL_AS void*)(bSrc[j] + kt),
                                             (LDS_AS void*)(B + bLds[j]), 16, 0, 0);
    };

    auto compute = [&](const int8_t* A, const int8_t* B) {
#pragma unroll
        for (int ks = 0; ks < 2; ++ks) {
            v4i a[4], b[2];
#pragma unroll
            for (int q = 0; q < 4; ++q) a[q] = *(const v4i*)(A + aOff[ks][q]);
#pragma unroll
            for (int q = 0; q < 2; ++q) b[q] = *(const v4i*)(B + bOff[ks][q]);
            __builtin_amdgcn_s_setprio(1);
#pragma unroll
            for (int mt = 0; mt < 4; ++mt)
#pragma unroll
                for (int nt = 0; nt < 2; ++nt)
                    acc[mt][nt] = __builtin_amdgcn_mfma_i32_32x32x32_i8(a[mt], b[nt], acc[mt][nt], 0, 0, 0);
            __builtin_amdgcn_s_setprio(0);
        }
    };

#define FENCE() asm volatile("" ::: "memory")
#define PIPE_STEP(NB, CB, KT)                                        \
    do {                                                             \
        stage((KT) * 64, As[NB], Bs[NB]);                            \
        asm volatile("s_waitcnt vmcnt(12)" ::: "memory");            \
        __builtin_amdgcn_s_barrier();                                \
        FENCE();                                                     \
        compute(As[CB], Bs[CB]);                                     \
        FENCE();                                                     \
        __builtin_amdgcn_s_barrier();                                \
        FENCE();                                                     \
    } while (0)

    // prologue: prefetch tiles 0,1,2
    stage(0, As[0], Bs[0]);
    stage(64, As[1], Bs[1]);
    stage(128, As[2], Bs[2]);

    // main: t = 0..55 (stages tiles 3..58), NIT = 64
#pragma unroll 1
    for (int tb = 0; tb < 56; tb += 4) {
        PIPE_STEP(3, 0, tb + 3);
        PIPE_STEP(0, 1, tb + 4);
        PIPE_STEP(1, 2, tb + 5);
        PIPE_STEP(2, 3, tb + 6);
    }
    // t = 56..60: stage tiles 59..63
    PIPE_STEP(3, 0, 59);
    PIPE_STEP(0, 1, 60);
    PIPE_STEP(1, 2, 61);
    PIPE_STEP(2, 3, 62);
    PIPE_STEP(3, 0, 63);
    // t = 61..63: drain
    asm volatile("s_waitcnt vmcnt(8)" ::: "memory");
    __builtin_amdgcn_s_barrier(); FENCE();
    compute(As[1], Bs[1]); FENCE();
    __builtin_amdgcn_s_barrier(); FENCE();
    asm volatile("s_waitcnt vmcnt(4)" ::: "memory");
    __builtin_amdgcn_s_barrier(); FENCE();
    compute(As[2], Bs[2]); FENCE();
    __builtin_amdgcn_s_barrier(); FENCE();
    asm volatile("s_waitcnt vmcnt(0)" ::: "memory");
    __builtin_amdgcn_s_barrier(); FENCE();
    compute(As[3], Bs[3]);
#undef PIPE_STEP
#undef FENCE

    // ---- epilogue: C/D layout col=lane&31, row=(reg&3)+8*(reg>>2)+4*(lane>>5) ----
    const float scale = wssc[2];
#pragma unroll
    for (int nt = 0; nt < 2; ++nt) {
        int col = n0 + wn0 + nt * 32 + lr;
        float bv = bias[col];
#pragma unroll
        for (int mt = 0; mt < 4; ++mt) {
            int rb = m0 + wm0 + mt * 32 + 4 * half;
#pragma unroll
            for (int reg = 0; reg < 16; ++reg) {
                int row = rb + (reg & 3) + 8 * (reg >> 2);
                out[(size_t)row * N + col] = (float)acc[mt][nt][reg] * scale + bv;
            }
        }
    }
}

extern "C" void kernel_launch(void* const* d_in, const int* in_sizes, int n_in,
                              void* d_out, int out_size, void* d_ws, size_t ws_size,
                              hipStream_t stream) {
    const float* x = (const float*)d_in[0];     // [8192][4096]
    const float* w = (const float*)d_in[1];     // [4096][4096]
    const float* bias = (const float*)d_in[2];  // [4096]
    float* out = (float*)d_out;                 // [8192][4096]

    float* wssc = (float*)d_ws;
    float* pmax = (float*)((char*)d_ws + 256);          // 2048 f32 -> ends 8448
    double* psum = (double*)((char*)d_ws + 8448);       // 1024 f64 -> ends 16640
    int8_t* xq = (int8_t*)d_ws + 16640;
    int8_t* wq = xq + (size_t)M * K;

    hipLaunchKernelGGL(reduce_kernel, dim3(3072), dim3(256), 0, stream,
                       (const float4*)x, (const float4*)w, pmax, psum);
    hipLaunchKernelGGL(finalize_kernel, dim3(1), dim3(256), 0, stream, wssc, pmax, psum);
    hipLaunchKernelGGL(quant_kernel, dim3(3072), dim3(256), 0, stream,
                       (const float4*)x, (const float4*)w, (int*)xq, (int*)wq, wssc);
    hipLaunchKernelGGL(gemm_kernel, dim3(M / 128 / 2 * N / 256 / 2 * 2), dim3(512), 0, stream,
                       xq, wq, bias, wssc, out);
}